// Round 1
// baseline (202.028 us; speedup 1.0000x reference)
//
#include <hip/hip_runtime.h>

#define BLOCK 256
#define NBLOCKS 1024
#define NBINS 256
#define NWAVES 4  // BLOCK / 64

// Per-wave privatized 256-bin LDS histogram over all global expert ids,
// then remap via expert_map and accumulate into the 64 local-expert counts.
__global__ __launch_bounds__(BLOCK) void hist_kernel(const int* __restrict__ ids,
                                                     int N,
                                                     const int* __restrict__ expert_map,
                                                     int* __restrict__ out,
                                                     int n_local) {
    __shared__ int lds[NWAVES * NBINS];
    const int tid = threadIdx.x;

    // Zero the privatized histograms.
    for (int i = tid; i < NWAVES * NBINS; i += BLOCK) lds[i] = 0;
    __syncthreads();

    int* h = &lds[(tid >> 6) * NBINS];

    const long long n4 = (long long)(N >> 2);  // number of int4 elements
    const int4* __restrict__ ids4 = (const int4*)ids;
    const long long stride = (long long)gridDim.x * BLOCK;

    for (long long i = (long long)blockIdx.x * BLOCK + tid; i < n4; i += stride) {
        int4 v = ids4[i];
        // ids are global expert ids in [0,256); mask only guards LDS bounds.
        atomicAdd(&h[v.x & (NBINS - 1)], 1);
        atomicAdd(&h[v.y & (NBINS - 1)], 1);
        atomicAdd(&h[v.z & (NBINS - 1)], 1);
        atomicAdd(&h[v.w & (NBINS - 1)], 1);
    }

    // Tail (N not divisible by 4) — handled once by block 0, lane-parallel.
    if (blockIdx.x == 0) {
        long long base = n4 << 2;
        for (long long i = base + tid; i < (long long)N; i += BLOCK) {
            atomicAdd(&h[ids[i] & (NBINS - 1)], 1);
        }
    }
    __syncthreads();

    // Epilogue: fold the NWAVES copies, remap, one global atomic per bin.
    if (tid < NBINS) {
        int sum = 0;
#pragma unroll
        for (int w = 0; w < NWAVES; ++w) sum += lds[w * NBINS + tid];
        int local = expert_map[tid];
        if (local >= 0 && local < n_local && sum > 0) {
            atomicAdd(&out[local], sum);
        }
    }
}

extern "C" void kernel_launch(void* const* d_in, const int* in_sizes, int n_in,
                              void* d_out, int out_size, void* d_ws, size_t ws_size,
                              hipStream_t stream) {
    const int* topk_ids = (const int*)d_in[0];
    // d_in[1] = num_local_experts (device scalar) — equal to out_size, use that.
    const int* expert_map = (const int*)d_in[2];
    const int N = in_sizes[0];
    const int n_local = out_size;

    // d_out is poisoned with 0xAA before every timed launch — zero it.
    hipMemsetAsync(d_out, 0, (size_t)n_local * sizeof(int), stream);

    hist_kernel<<<NBLOCKS, BLOCK, 0, stream>>>(topk_ids, N, expert_map,
                                               (int*)d_out, n_local);
}

// Round 2
// 199.856 us; speedup vs baseline: 1.0109x; 1.0109x over previous
//
#include <hip/hip_runtime.h>

#define BLOCK   256
#define NB1     2048          // histogram blocks (8 per CU)
#define NBINS   256           // global expert-id bins
#define NWAVES  (BLOCK / 64)
#define UNROLL  4             // int4 loads per thread per grid-stride iter

// Kernel 1: per-wave privatized 256-bin LDS histogram over global expert ids,
// per-block partial counts written to ws (bin-major: partials[bin*NB1 + block]).
// No global atomics here.
__global__ __launch_bounds__(BLOCK) void hist_part(const int* __restrict__ ids,
                                                   int N,
                                                   int* __restrict__ partials) {
    __shared__ int lds[NWAVES * NBINS];
    const int tid = threadIdx.x;
    for (int i = tid; i < NWAVES * NBINS; i += BLOCK) lds[i] = 0;
    __syncthreads();

    int* h = &lds[(tid >> 6) * NBINS];

    const int4* __restrict__ ids4 = (const int4*)ids;
    const int n4      = N >> 2;
    const int chunk   = BLOCK * UNROLL;              // int4 per block per iter
    const int gstride = (int)gridDim.x * chunk;
    const int n4_full = (n4 / gstride) * gstride;

    // Main loop: issue 4 independent coalesced 16B loads before any LDS work
    // so each wave keeps 64B/lane in flight (latency hiding), then histogram.
    for (int i = (int)blockIdx.x * chunk + tid; i < n4_full; i += gstride) {
        int4 v[UNROLL];
#pragma unroll
        for (int u = 0; u < UNROLL; ++u) v[u] = ids4[i + u * BLOCK];
#pragma unroll
        for (int u = 0; u < UNROLL; ++u) {
            atomicAdd(&h[v[u].x & (NBINS - 1)], 1);
            atomicAdd(&h[v[u].y & (NBINS - 1)], 1);
            atomicAdd(&h[v[u].z & (NBINS - 1)], 1);
            atomicAdd(&h[v[u].w & (NBINS - 1)], 1);
        }
    }
    // int4 tail
    for (int i = n4_full + (int)blockIdx.x * BLOCK + tid; i < n4;
         i += (int)gridDim.x * BLOCK) {
        int4 v = ids4[i];
        atomicAdd(&h[v.x & (NBINS - 1)], 1);
        atomicAdd(&h[v.y & (NBINS - 1)], 1);
        atomicAdd(&h[v.z & (NBINS - 1)], 1);
        atomicAdd(&h[v.w & (NBINS - 1)], 1);
    }
    // scalar tail (N % 4), one block
    if (blockIdx.x == 0) {
        for (int i = (n4 << 2) + tid; i < N; i += BLOCK)
            atomicAdd(&h[ids[i] & (NBINS - 1)], 1);
    }
    __syncthreads();

    // Fold the NWAVES copies; write per-block partial (bin-major so kernel 2
    // reads coalesced). Every block writes all 256 bins -> no poison residue.
    for (int b = tid; b < NBINS; b += BLOCK) {
        int s = 0;
#pragma unroll
        for (int w = 0; w < NWAVES; ++w) s += lds[w * NBINS + b];
        partials[b * NB1 + blockIdx.x] = s;
    }
}

// Kernel 2: one block per global bin; coalesced sum of NB1 partials,
// remap via expert_map, exactly one global atomic per mapped bin (256 total).
__global__ __launch_bounds__(BLOCK) void reduce_part(const int* __restrict__ partials,
                                                     const int* __restrict__ emap,
                                                     int emap_n,
                                                     int* __restrict__ out,
                                                     int n_local) {
    const int g = blockIdx.x;
    const int tid = threadIdx.x;
    int s = 0;
    for (int j = tid; j < NB1; j += BLOCK) s += partials[g * NB1 + j];
#pragma unroll
    for (int off = 32; off > 0; off >>= 1) s += __shfl_down(s, off, 64);
    __shared__ int wsum[NWAVES];
    if ((tid & 63) == 0) wsum[tid >> 6] = s;
    __syncthreads();
    if (tid == 0) {
        int tot = 0;
#pragma unroll
        for (int w = 0; w < NWAVES; ++w) tot += wsum[w];
        int l = (g < emap_n) ? emap[g] : -1;
        if ((unsigned)l < (unsigned)n_local && tot != 0) atomicAdd(&out[l], tot);
    }
}

extern "C" void kernel_launch(void* const* d_in, const int* in_sizes, int n_in,
                              void* d_out, int out_size, void* d_ws, size_t ws_size,
                              hipStream_t stream) {
    const int* topk_ids   = (const int*)d_in[0];
    // d_in[1] = num_local_experts (device scalar) == out_size; use out_size.
    const int* expert_map = (const int*)d_in[2];
    const int N       = in_sizes[0];
    const int emap_n  = in_sizes[2];
    const int n_local = out_size;

    int* partials = (int*)d_ws;  // NBINS * NB1 ints = 2 MB

    // d_out poisoned with 0xAA each iter; not every local bin is guaranteed a
    // writer in the general case -> zero it.
    hipMemsetAsync(d_out, 0, (size_t)n_local * sizeof(int), stream);

    hist_part<<<NB1, BLOCK, 0, stream>>>(topk_ids, N, partials);
    reduce_part<<<NBINS, BLOCK, 0, stream>>>(partials, expert_map, emap_n,
                                             (int*)d_out, n_local);
}

// Round 3
// 196.385 us; speedup vs baseline: 1.0287x; 1.0177x over previous
//
#include <hip/hip_runtime.h>

#define BLOCK   256
#define NB1     2048          // histogram blocks (8 per CU)
#define NBINS   256           // global expert-id space
#define NWAVES  (BLOCK / 64)
#define UNROLL  4             // int4 loads per thread per grid-stride iter

// ws layout: [0..2] params {lo, cnt, affine}; partials start at +4096.
#define PARTIALS_OFF 4096

// Kernel 0: analyze expert_map. If it is an affine contiguous window
// (local = g - lo for g in [lo, lo+cnt), -1 elsewhere) set affine=1 so the
// hist kernel can test validity arithmetically (no per-element remap load).
__global__ __launch_bounds__(BLOCK) void prep(const int* __restrict__ emap,
                                              int emap_n,
                                              int* __restrict__ params) {
    __shared__ int s_min, s_cnt, s_ok;
    const int tid = threadIdx.x;
    if (tid == 0) { s_min = 0x7FFFFFFF; s_cnt = 0; s_ok = 1; }
    __syncthreads();
    for (int g = tid; g < emap_n; g += BLOCK) {
        if (emap[g] >= 0) { atomicMin(&s_min, g); atomicAdd(&s_cnt, 1); }
    }
    __syncthreads();
    const int lo = s_min, cnt = s_cnt;
    for (int g = tid; g < emap_n; g += BLOCK) {
        int expect = (g >= lo && g < lo + cnt) ? (g - lo) : -1;
        if (emap[g] != expect) atomicAnd(&s_ok, 0);
    }
    __syncthreads();
    if (tid == 0) { params[0] = lo; params[1] = cnt; params[2] = s_ok; }
}

// Kernel 1: per-wave privatized LDS histogram. Fast path: arithmetic
// validity test (~25% active lanes on the atomic). Slow path: LDS remap.
__global__ __launch_bounds__(BLOCK) void hist_part(const int* __restrict__ ids,
                                                   int N,
                                                   const int* __restrict__ params,
                                                   const int* __restrict__ emap,
                                                   int emap_n,
                                                   int* __restrict__ partials,
                                                   int n_local) {
    __shared__ int hist[NWAVES * NBINS];
    __shared__ int lmap[NBINS];
    const int tid = threadIdx.x;
    const int lo = params[0];
    const unsigned cnt = (unsigned)params[1];
    const int affine = params[2];

    for (int i = tid; i < NWAVES * NBINS; i += BLOCK) hist[i] = 0;
    if (!affine) {
        for (int i = tid; i < NBINS; i += BLOCK)
            lmap[i] = (i < emap_n) ? emap[i] : -1;
    }
    __syncthreads();

    int* h = &hist[(tid >> 6) * NBINS];

    const int4* __restrict__ ids4 = (const int4*)ids;
    const int n4      = N >> 2;
    const int chunk   = BLOCK * UNROLL;
    const int gstride = (int)gridDim.x * chunk;
    const int n4_full = (n4 / gstride) * gstride;

    if (affine) {
        for (int i = (int)blockIdx.x * chunk + tid; i < n4_full; i += gstride) {
            int4 v[UNROLL];
#pragma unroll
            for (int u = 0; u < UNROLL; ++u) v[u] = ids4[i + u * BLOCK];
#pragma unroll
            for (int u = 0; u < UNROLL; ++u) {
                unsigned a = (unsigned)(v[u].x - lo);
                unsigned b = (unsigned)(v[u].y - lo);
                unsigned c = (unsigned)(v[u].z - lo);
                unsigned d = (unsigned)(v[u].w - lo);
                if (a < cnt) atomicAdd(&h[a], 1);
                if (b < cnt) atomicAdd(&h[b], 1);
                if (c < cnt) atomicAdd(&h[c], 1);
                if (d < cnt) atomicAdd(&h[d], 1);
            }
        }
        for (int i = n4_full + (int)blockIdx.x * BLOCK + tid; i < n4;
             i += (int)gridDim.x * BLOCK) {
            int4 v = ids4[i];
            unsigned a = (unsigned)(v.x - lo), b = (unsigned)(v.y - lo);
            unsigned c = (unsigned)(v.z - lo), d = (unsigned)(v.w - lo);
            if (a < cnt) atomicAdd(&h[a], 1);
            if (b < cnt) atomicAdd(&h[b], 1);
            if (c < cnt) atomicAdd(&h[c], 1);
            if (d < cnt) atomicAdd(&h[d], 1);
        }
        if (blockIdx.x == 0) {
            for (int i = (n4 << 2) + tid; i < N; i += BLOCK) {
                unsigned a = (unsigned)(ids[i] - lo);
                if (a < cnt) atomicAdd(&h[a], 1);
            }
        }
    } else {
        for (int i = (int)blockIdx.x * chunk + tid; i < n4_full; i += gstride) {
            int4 v[UNROLL];
#pragma unroll
            for (int u = 0; u < UNROLL; ++u) v[u] = ids4[i + u * BLOCK];
#pragma unroll
            for (int u = 0; u < UNROLL; ++u) {
                int l0 = ((unsigned)v[u].x < NBINS) ? lmap[v[u].x] : -1;
                int l1 = ((unsigned)v[u].y < NBINS) ? lmap[v[u].y] : -1;
                int l2 = ((unsigned)v[u].z < NBINS) ? lmap[v[u].z] : -1;
                int l3 = ((unsigned)v[u].w < NBINS) ? lmap[v[u].w] : -1;
                if (l0 >= 0) atomicAdd(&h[l0], 1);
                if (l1 >= 0) atomicAdd(&h[l1], 1);
                if (l2 >= 0) atomicAdd(&h[l2], 1);
                if (l3 >= 0) atomicAdd(&h[l3], 1);
            }
        }
        for (int i = n4_full + (int)blockIdx.x * BLOCK + tid; i < n4;
             i += (int)gridDim.x * BLOCK) {
            int4 v = ids4[i];
            int l0 = ((unsigned)v.x < NBINS) ? lmap[v.x] : -1;
            int l1 = ((unsigned)v.y < NBINS) ? lmap[v.y] : -1;
            int l2 = ((unsigned)v.z < NBINS) ? lmap[v.z] : -1;
            int l3 = ((unsigned)v.w < NBINS) ? lmap[v.w] : -1;
            if (l0 >= 0) atomicAdd(&h[l0], 1);
            if (l1 >= 0) atomicAdd(&h[l1], 1);
            if (l2 >= 0) atomicAdd(&h[l2], 1);
            if (l3 >= 0) atomicAdd(&h[l3], 1);
        }
        if (blockIdx.x == 0) {
            for (int i = (n4 << 2) + tid; i < N; i += BLOCK) {
                int v = ids[i];
                int l = ((unsigned)v < NBINS) ? lmap[v] : -1;
                if (l >= 0) atomicAdd(&h[l], 1);
            }
        }
    }
    __syncthreads();

    // Fold wave copies; write per-block partials for the n_local bins only.
    for (int b = tid; b < n_local; b += BLOCK) {
        int s = 0;
#pragma unroll
        for (int w = 0; w < NWAVES; ++w) s += hist[w * NBINS + b];
        partials[b * NB1 + blockIdx.x] = s;
    }
}

// Kernel 2: one block per LOCAL bin; coalesced sum, direct store (covers
// every output element each call -> no memset needed).
__global__ __launch_bounds__(BLOCK) void reduce_part(const int* __restrict__ partials,
                                                     int* __restrict__ out) {
    const int b = blockIdx.x;
    const int tid = threadIdx.x;
    int s = 0;
    for (int j = tid; j < NB1; j += BLOCK) s += partials[b * NB1 + j];
#pragma unroll
    for (int off = 32; off > 0; off >>= 1) s += __shfl_down(s, off, 64);
    __shared__ int wsum[NWAVES];
    if ((tid & 63) == 0) wsum[tid >> 6] = s;
    __syncthreads();
    if (tid == 0) {
        int tot = 0;
#pragma unroll
        for (int w = 0; w < NWAVES; ++w) tot += wsum[w];
        out[b] = tot;
    }
}

extern "C" void kernel_launch(void* const* d_in, const int* in_sizes, int n_in,
                              void* d_out, int out_size, void* d_ws, size_t ws_size,
                              hipStream_t stream) {
    const int* topk_ids   = (const int*)d_in[0];
    // d_in[1] = num_local_experts (device scalar) == out_size; use out_size.
    const int* expert_map = (const int*)d_in[2];
    const int N       = in_sizes[0];
    const int emap_n  = in_sizes[2];
    const int n_local = out_size;

    int* params   = (int*)d_ws;
    int* partials = (int*)((char*)d_ws + PARTIALS_OFF);  // n_local*NB1 ints

    prep<<<1, BLOCK, 0, stream>>>(expert_map, emap_n, params);
    hist_part<<<NB1, BLOCK, 0, stream>>>(topk_ids, N, params, expert_map,
                                         emap_n, partials, n_local);
    reduce_part<<<n_local, BLOCK, 0, stream>>>(partials, (int*)d_out);
}

// Round 4
// 195.844 us; speedup vs baseline: 1.0316x; 1.0028x over previous
//
#include <hip/hip_runtime.h>

#define BLOCK   256
#define NB1     2048          // histogram blocks (8 per CU)
#define NBINS   256           // global expert-id space
#define NWAVES  (BLOCK / 64)
#define UNROLL  4             // int4 loads per thread per grid-stride iter

// Kernel 1: per-wave privatized LDS histogram with INLINE affine-map
// detection (expert_map is 1 KB, L1/L2-resident; per-block detect costs
// ~hundreds of cycles and removes the separate prep dispatch).
// Fast path: validity test is arithmetic (u = id - lo < cnt).
// Slow path: LDS remap table.
// Per-block partials written bin-major to ws; no global atomics.
__global__ __launch_bounds__(BLOCK) void hist_part(const int* __restrict__ ids,
                                                   int N,
                                                   const int* __restrict__ emap,
                                                   int emap_n,
                                                   int* __restrict__ partials,
                                                   int n_local) {
    __shared__ int hist[NWAVES * NBINS];
    __shared__ int lmap[NBINS];
    __shared__ int s_lo, s_cnt, s_ok;
    const int tid = threadIdx.x;

    if (tid == 0) { s_lo = 0x7FFFFFFF; s_cnt = 0; s_ok = 1; }
    for (int i = tid; i < NWAVES * NBINS; i += BLOCK) hist[i] = 0;
    __syncthreads();

    // Pass 1: window min + count of valid entries; stash map in LDS.
    for (int g = tid; g < NBINS; g += BLOCK) {
        int m = (g < emap_n) ? emap[g] : -1;
        lmap[g] = m;
        if (m >= 0) { atomicMin(&s_lo, g); atomicAdd(&s_cnt, 1); }
    }
    __syncthreads();
    const int lo = s_lo;
    const unsigned cnt = (unsigned)s_cnt;
    // Pass 2: verify map is exactly the affine window g -> g - lo.
    for (int g = tid; g < NBINS; g += BLOCK) {
        int expect = (g >= lo && (unsigned)(g - lo) < cnt) ? (g - lo) : -1;
        if (lmap[g] != expect) s_ok = 0;   // benign race, all writers store 0
    }
    __syncthreads();
    const int affine = s_ok;

    int* h = &hist[(tid >> 6) * NBINS];

    const int4* __restrict__ ids4 = (const int4*)ids;
    const int n4      = N >> 2;
    const int chunk   = BLOCK * UNROLL;
    const int gstride = (int)gridDim.x * chunk;
    const int n4_full = (n4 / gstride) * gstride;

    if (affine) {
        for (int i = (int)blockIdx.x * chunk + tid; i < n4_full; i += gstride) {
            int4 v[UNROLL];
#pragma unroll
            for (int u = 0; u < UNROLL; ++u) v[u] = ids4[i + u * BLOCK];
#pragma unroll
            for (int u = 0; u < UNROLL; ++u) {
                unsigned a = (unsigned)(v[u].x - lo);
                unsigned b = (unsigned)(v[u].y - lo);
                unsigned c = (unsigned)(v[u].z - lo);
                unsigned d = (unsigned)(v[u].w - lo);
                if (a < cnt) atomicAdd(&h[a], 1);
                if (b < cnt) atomicAdd(&h[b], 1);
                if (c < cnt) atomicAdd(&h[c], 1);
                if (d < cnt) atomicAdd(&h[d], 1);
            }
        }
        for (int i = n4_full + (int)blockIdx.x * BLOCK + tid; i < n4;
             i += (int)gridDim.x * BLOCK) {
            int4 v = ids4[i];
            unsigned a = (unsigned)(v.x - lo), b = (unsigned)(v.y - lo);
            unsigned c = (unsigned)(v.z - lo), d = (unsigned)(v.w - lo);
            if (a < cnt) atomicAdd(&h[a], 1);
            if (b < cnt) atomicAdd(&h[b], 1);
            if (c < cnt) atomicAdd(&h[c], 1);
            if (d < cnt) atomicAdd(&h[d], 1);
        }
        if (blockIdx.x == 0) {
            for (int i = (n4 << 2) + tid; i < N; i += BLOCK) {
                unsigned a = (unsigned)(ids[i] - lo);
                if (a < cnt) atomicAdd(&h[a], 1);
            }
        }
    } else {
        for (int i = (int)blockIdx.x * chunk + tid; i < n4_full; i += gstride) {
            int4 v[UNROLL];
#pragma unroll
            for (int u = 0; u < UNROLL; ++u) v[u] = ids4[i + u * BLOCK];
#pragma unroll
            for (int u = 0; u < UNROLL; ++u) {
                int l0 = ((unsigned)v[u].x < NBINS) ? lmap[v[u].x] : -1;
                int l1 = ((unsigned)v[u].y < NBINS) ? lmap[v[u].y] : -1;
                int l2 = ((unsigned)v[u].z < NBINS) ? lmap[v[u].z] : -1;
                int l3 = ((unsigned)v[u].w < NBINS) ? lmap[v[u].w] : -1;
                if (l0 >= 0) atomicAdd(&h[l0], 1);
                if (l1 >= 0) atomicAdd(&h[l1], 1);
                if (l2 >= 0) atomicAdd(&h[l2], 1);
                if (l3 >= 0) atomicAdd(&h[l3], 1);
            }
        }
        for (int i = n4_full + (int)blockIdx.x * BLOCK + tid; i < n4;
             i += (int)gridDim.x * BLOCK) {
            int4 v = ids4[i];
            int l0 = ((unsigned)v.x < NBINS) ? lmap[v.x] : -1;
            int l1 = ((unsigned)v.y < NBINS) ? lmap[v.y] : -1;
            int l2 = ((unsigned)v.z < NBINS) ? lmap[v.z] : -1;
            int l3 = ((unsigned)v.w < NBINS) ? lmap[v.w] : -1;
            if (l0 >= 0) atomicAdd(&h[l0], 1);
            if (l1 >= 0) atomicAdd(&h[l1], 1);
            if (l2 >= 0) atomicAdd(&h[l2], 1);
            if (l3 >= 0) atomicAdd(&h[l3], 1);
        }
        if (blockIdx.x == 0) {
            for (int i = (n4 << 2) + tid; i < N; i += BLOCK) {
                int v = ids[i];
                int l = ((unsigned)v < NBINS) ? lmap[v] : -1;
                if (l >= 0) atomicAdd(&h[l], 1);
            }
        }
    }
    __syncthreads();

    // Fold wave copies; per-block partials, bin-major for coalesced reduce.
    for (int b = tid; b < n_local; b += BLOCK) {
        int s = 0;
#pragma unroll
        for (int w = 0; w < NWAVES; ++w) s += hist[w * NBINS + b];
        partials[b * NB1 + blockIdx.x] = s;
    }
}

// Kernel 2: one block per LOCAL bin; coalesced sum, direct store (every
// output element written each call -> no memset of d_out needed).
__global__ __launch_bounds__(BLOCK) void reduce_part(const int* __restrict__ partials,
                                                     int* __restrict__ out) {
    const int b = blockIdx.x;
    const int tid = threadIdx.x;
    int s = 0;
    for (int j = tid; j < NB1; j += BLOCK) s += partials[b * NB1 + j];
#pragma unroll
    for (int off = 32; off > 0; off >>= 1) s += __shfl_down(s, off, 64);
    __shared__ int wsum[NWAVES];
    if ((tid & 63) == 0) wsum[tid >> 6] = s;
    __syncthreads();
    if (tid == 0) {
        int tot = 0;
#pragma unroll
        for (int w = 0; w < NWAVES; ++w) tot += wsum[w];
        out[b] = tot;
    }
}

extern "C" void kernel_launch(void* const* d_in, const int* in_sizes, int n_in,
                              void* d_out, int out_size, void* d_ws, size_t ws_size,
                              hipStream_t stream) {
    const int* topk_ids   = (const int*)d_in[0];
    // d_in[1] = num_local_experts (device scalar) == out_size; use out_size.
    const int* expert_map = (const int*)d_in[2];
    const int N       = in_sizes[0];
    const int emap_n  = in_sizes[2];
    const int n_local = out_size;

    int* partials = (int*)d_ws;  // n_local * NB1 ints (<= 2 MB)

    hist_part<<<NB1, BLOCK, 0, stream>>>(topk_ids, N, expert_map, emap_n,
                                         partials, n_local);
    reduce_part<<<n_local, BLOCK, 0, stream>>>(partials, (int*)d_out);
}